// Round 1
// baseline (193.107 us; speedup 1.0000x reference)
//
#include <hip/hip_runtime.h>
#include <hip/hip_bf16.h>

#define NN 50000
#define FIN 128
#define NT (NN / 16)   // 3125 row-tiles of 16
#define NREG 196       // ceil(NN/256) 256-node regions
#define RCAP 5120      // bucket capacity per region (mean 4082, +16 sigma)
#define SLAB 8960      // fixed per-region CSR slab (RCAP + 256*15, x16-aligned)
#define NB_AGG ((NN + 31) / 32)  // agg blocks: 32 nodes/block (8 per wave)

typedef unsigned short u16;
typedef unsigned int u32;
typedef __attribute__((ext_vector_type(8))) short short8;
typedef __attribute__((ext_vector_type(4))) float floatx4;

__device__ __forceinline__ float b2f(u16 v) {
  union { u32 u; float f; } x; x.u = ((u32)v) << 16; return x.f;
}
__device__ __forceinline__ u16 f2b(float f) {
  union { u32 u; float f; } x; x.f = f;
  u32 r = x.u + 0x7FFFu + ((x.u >> 16) & 1u);  // round-nearest-even
  return (u16)(r >> 16);
}

// Fused prep + bucket phase A.
// Blocks 0..31: W1 frag hi/lo tables (block 0 detects x/W1, publishes flags).
// Block 32: w2f = W2@Wfc, cbias, zero g0/g1 sentinel rows + tvec sentinel.
// Blocks 33..288: binA (edge streaming -> region buckets + global cnt atomics).
__global__ __launch_bounds__(256) void k_prep_binA(
    const u32* __restrict__ xw, int nxw, const void* __restrict__ w1, int n1w,
    const void* __restrict__ w2, int n2w, const void* __restrict__ wf, int nfw,
    const u16* __restrict__ b2, const u16* __restrict__ bfc,
    u16* __restrict__ W1h, u16* __restrict__ W1l, float* __restrict__ w2f,
    float* __restrict__ cbias, int* __restrict__ flags,
    const int* __restrict__ src, const int* __restrict__ dst, int E,
    u32* __restrict__ bucket, int* __restrict__ gtail, int* __restrict__ cnt,
    u16* __restrict__ g0, u16* __restrict__ g1, float* __restrict__ tvec) {
  int t = threadIdx.x;
  int blk = blockIdx.x;
  if (blk >= 33) {  // ---- binA ----
    __shared__ int hist[NREG];
    __shared__ int base[NREG];
    for (int i = t; i < NREG; i += 256) hist[i] = 0;
    __syncthreads();
    int sl = blk - 33, nsl = 256;
    int lo = (int)((long long)sl * E / nsl);
    int hi = (int)((long long)(sl + 1) * E / nsl);
    for (int e = lo + t; e < hi; e += 256) {
      int d = dst[e];
      atomicAdd(&hist[d >> 8], 1);
      atomicAdd(&cnt[d], 1);  // fire-and-forget global degree count
    }
    __syncthreads();
    for (int i = t; i < NREG; i += 256) {
      int c = hist[i];
      base[i] = (c > 0) ? atomicAdd(&gtail[i], c) : 0;
      hist[i] = 0;
    }
    __syncthreads();
    for (int e = lo + t; e < hi; e += 256) {
      int d = dst[e];
      int r = d >> 8;
      int ofs = base[r] + atomicAdd(&hist[r], 1);
      if (ofs < RCAP)
        bucket[(size_t)r * RCAP + ofs] = ((u32)(d & 255) << 16) | (u32)src[e];
    }
    return;
  }
  __shared__ int sc[2];
  if (t < 2) sc[t] = 0;
  __syncthreads();
  if (blk < 32) {  // ---- W1 frag tables ----
    const u32* p = (const u32*)w1;
    int samples = n1w < 1024 ? n1w : 1024;
    int score = 0;
    for (int i = t; i < samples; i += 256) {
      u32 w = p[i];
      u32 e = (w >> 7) & 0xFFu;
      score += (e >= 100u && e <= 132u) ? 1 : -1;
    }
    if (score) atomicAdd(&sc[0], score);
    if (blk == 0) {
      int sn = nxw < 1024 ? nxw : 1024;
      int sx = 0;
      for (int i = t; i < sn; i += 256) {
        u32 w = xw[i];
        u32 e = (w >> 7) & 0xFFu;
        sx += (e >= 100u && e <= 132u) ? 1 : -1;
      }
      if (sx) atomicAdd(&sc[1], sx);
    }
    __syncthreads();
    int f1 = sc[0] > 0;
    if (blk == 0 && t == 0) {
      flags[0] = sc[1] > 0;
      flags[1] = f1;
    }
    int i = blk * 256 + t;
    int j = i & 7, L = (i >> 3) & 63, f = i >> 9;
    int k = (f >> 2) * 32 + (L >> 4) * 8 + j;
    int n = (f & 3) * 16 + (L & 15);
    int idx = k * 64 + n;
    float v = f1 ? b2f(((const u16*)w1)[idx]) : ((const float*)w1)[idx];
    u16 hb = f2b(v);
    W1h[i] = hb;
    W1l[i] = f2b(v - b2f(hb));
  } else {  // ---- blk == 32: w2f, cbias, sentinels ----
    const u32* p2 = (const u32*)w2;
    const u32* pf = (const u32*)wf;
    int n2s = n2w < 1024 ? n2w : 1024;
    int nfs = nfw < 1024 ? nfw : 1024;
    int s2 = 0, sf = 0;
    for (int i = t; i < n2s; i += 256) {
      u32 w = p2[i];
      u32 e = (w >> 7) & 0xFFu;
      s2 += (e >= 100u && e <= 132u) ? 1 : -1;
    }
    for (int i = t; i < nfs; i += 256) {
      u32 w = pf[i];
      u32 e = (w >> 7) & 0xFFu;
      sf += (e >= 100u && e <= 132u) ? 1 : -1;
    }
    if (s2) atomicAdd(&sc[0], s2);
    if (sf) atomicAdd(&sc[1], sf);
    __syncthreads();
    int f2 = sc[0] > 0, f3 = sc[1] > 0;
    if (t == 0) { flags[2] = f2; flags[3] = f3; }
    if (t < 64) {
      float acc = 0.f;
      for (int j = 0; j < 64; ++j) {
        float w2v = f2 ? b2f(((const u16*)w2)[t * 64 + j])
                       : ((const float*)w2)[t * 64 + j];
        float wfv = f3 ? b2f(((const u16*)wf)[j]) : ((const float*)wf)[j];
        acc += w2v * wfv;
      }
      w2f[t] = acc;
    } else if (t == 64) {
      float acc = b2f(bfc[0]);
      for (int j = 0; j < 64; ++j) {
        float wfv = f3 ? b2f(((const u16*)wf)[j]) : ((const float*)wf)[j];
        acc += b2f(b2[j]) * wfv;
      }
      cbias[0] = acc;
    } else if (t >= 128 && t < 160) {
      g0[(size_t)NN * 32 + (t - 128)] = 0;  // sentinel row g0[NN] = 0
    } else if (t >= 160 && t < 192) {
      g1[(size_t)NN * 32 + (t - 160)] = 0;  // sentinel row g1[NN] = 0
    } else if (t == 192) {
      tvec[NN] = 0.f;  // sentinel tscaled[NN] = 0
    }
  }
}

// Fused: blocks 0..195 = region scan (cnt -> rowstart) + CSR scatter + pad;
// blocks 196.. = split-bf16 MFMA GEMM with dinv-scaled bf16 output split into
// two half-feature tables g0 (cols 0..31) and g1 (cols 32..63), 3.2 MB each
// so the layer-1 gather working set fits a per-XCD L2.
__global__ __launch_bounds__(256) void k_gemm_scatter(
    const u32* __restrict__ bucket, const int* __restrict__ gtail,
    int* __restrict__ rowstart, const int* __restrict__ cnt,
    u16* __restrict__ csr,
    const void* __restrict__ X, const u16* __restrict__ Wh,
    const u16* __restrict__ Wl, u16* __restrict__ g0, u16* __restrict__ g1,
    const int* __restrict__ flags) {
  int t = threadIdx.x;
  if (blockIdx.x < NREG) {  // ---- scan + scatter + pad ----
    __shared__ int off[256];
    __shared__ int sm4[4];
    int r = blockIdx.x;
    int v = r * 256 + t;
    int c = (v < NN) ? cnt[v] : 0;
    int p = (c + 15) & ~15;
    int lane = t & 63, w = t >> 6;
    int xv = p;
    for (int d = 1; d < 64; d <<= 1) {
      int y = __shfl_up(xv, d);
      if (lane >= d) xv += y;
    }
    if (lane == 63) sm4[w] = xv;
    __syncthreads();
    int add = 0;
    for (int j2 = 0; j2 < w; ++j2) add += sm4[j2];
    xv += add;
    int grs = r * SLAB + xv - p;  // exclusive padded scan within slab
    if (v < NN) rowstart[v] = grs;
    off[t] = grs;
    __syncthreads();
    int n = gtail[r];
    if (n > RCAP) n = RCAP;
    const u32* b = bucket + (size_t)r * RCAP;
    for (int i = t; i < n; i += 256) {
      u32 pk = b[i];
      int pos = atomicAdd(&off[pk >> 16], 1);
      csr[pos] = (u16)(pk & 0xFFFFu);
    }
    __syncthreads();
    if (v < NN) {
      int end = grs + p;
      for (int pos = off[t]; pos < end; ++pos) csr[pos] = (u16)NN;  // sentinel
    }
    return;
  }
  // ---- GEMM: g0|g1 = bf16(dinv[row] * (x @ W1)) ----
  constexpr int KC = FIN / 32;
  int wave = t >> 6, lane = t & 63;
  int rt = (blockIdx.x - NREG) * 4 + wave;
  if (rt >= NT) return;
  int m = rt * 16 + (lane & 15);
  int q = (lane >> 4) * 8;
  bool xb = flags[0] != 0;

  short8 ah[KC], al[KC];
  if (xb) {
    const u16* xr = (const u16*)X + (size_t)m * FIN + q;
#pragma unroll
    for (int kc = 0; kc < KC; ++kc) ah[kc] = *(const short8*)(xr + kc * 32);
  } else {
    const float* xr = (const float*)X + (size_t)m * FIN + q;
#pragma unroll
    for (int kc = 0; kc < KC; ++kc) {
      float4 v0 = *(const float4*)(xr + kc * 32);
      float4 v1 = *(const float4*)(xr + kc * 32 + 4);
      float v[8] = {v0.x, v0.y, v0.z, v0.w, v1.x, v1.y, v1.z, v1.w};
      short8 h8, l8;
#pragma unroll
      for (int j = 0; j < 8; ++j) {
        u16 hb = f2b(v[j]);
        h8[j] = (short)hb;
        l8[j] = (short)f2b(v[j] - b2f(hb));
      }
      ah[kc] = h8;
      al[kc] = l8;
    }
  }

  int row0 = rt * 16 + (lane >> 4) * 4;
  int c0 = lane & 15;
  float dvr[4];
#pragma unroll
  for (int r = 0; r < 4; ++r)
    dvr[r] = rsqrtf((float)(cnt[row0 + r] + 1));
#pragma unroll
  for (int ct = 0; ct < 4; ++ct) {
    short8 bh[KC], bl[KC];
#pragma unroll
    for (int kc = 0; kc < KC; ++kc) {
      size_t fo = ((size_t)((kc * 4 + ct) * 64 + lane)) * 8;
      bh[kc] = *(const short8*)(Wh + fo);
      bl[kc] = *(const short8*)(Wl + fo);
    }
    floatx4 acc = (floatx4)(0.f);
#pragma unroll
    for (int kc = 0; kc < KC; ++kc) {
      if (!xb)
        acc = __builtin_amdgcn_mfma_f32_16x16x32_bf16(al[kc], bh[kc], acc, 0, 0, 0);
      acc = __builtin_amdgcn_mfma_f32_16x16x32_bf16(ah[kc], bl[kc], acc, 0, 0, 0);
      acc = __builtin_amdgcn_mfma_f32_16x16x32_bf16(ah[kc], bh[kc], acc, 0, 0, 0);
    }
#pragma unroll
    for (int r = 0; r < 4; ++r) {
      u16 ov = f2b(acc[r] * dvr[r]);
      if (ct < 2)
        g0[(size_t)(row0 + r) * 32 + ct * 16 + c0] = ov;
      else
        g1[(size_t)(row0 + r) * 32 + (ct - 2) * 16 + c0] = ov;
    }
  }
}

// Layer-1 agg + relu + head projection over ONE half-feature table (32 cols).
// Column-separable through the relu: val = sum_c relu(dv*agg_c + b1_c)*w2f_c.
// Wave = 8 dst nodes (4 per 32-lane half); each gather instruction serves two
// edges at 64 B each, all hitting the L2-resident 3.2 MB half-table.
// pass 0: tvec[v]  = dv * val(g0);  pass 1: tvec[v] += dv * val(g1).
__global__ __launch_bounds__(256) void k_agg1p(const u16* __restrict__ gp,
                                               const int* __restrict__ rowstart,
                                               const int* __restrict__ cnt,
                                               const u16* __restrict__ csr,
                                               const u16* __restrict__ bias,
                                               const float* __restrict__ w2f,
                                               float* __restrict__ tvec,
                                               int pass) {
  int tid = threadIdx.x;
  int wave = tid >> 6, lane = tid & 63;
  int h = lane >> 5, col = lane & 31;
  int vb = (blockIdx.x * 4 + wave) * 8 + h * 4;  // this half's first node
  int rs[4], pd[4];
  float dvl[4], acc[4];
  bool ok[4];
  int pm = 0;
#pragma unroll
  for (int n = 0; n < 4; ++n) {
    int nv = vb + n;
    ok[n] = nv < NN;
    int cv = ok[n] ? nv : 0;
    int c = ok[n] ? cnt[cv] : 0;
    rs[n] = rowstart[cv];
    pd[n] = ok[n] ? ((c + 15) & ~15) : 0;
    dvl[n] = rsqrtf((float)(c + 1));
    acc[n] = ok[n] ? b2f(gp[(size_t)cv * 32 + col]) : 0.f;  // self term
    pm = pd[n] > pm ? pd[n] : pm;
  }
  for (int j = 0; j < pm; j += 16) {
    u32 cw[4][8];
    bool act[4];
#pragma unroll
    for (int n = 0; n < 4; ++n) {
      act[n] = j < pd[n];
      if (act[n]) {
        int b = rs[n] + j;
        uint4 uq0 = *(const uint4*)(csr + b);
        uint4 uq1 = *(const uint4*)(csr + b + 8);
        cw[n][0] = uq0.x; cw[n][1] = uq0.y; cw[n][2] = uq0.z; cw[n][3] = uq0.w;
        cw[n][4] = uq1.x; cw[n][5] = uq1.y; cw[n][6] = uq1.z; cw[n][7] = uq1.w;
      }
    }
    float hh[4][16];
#pragma unroll
    for (int n = 0; n < 4; ++n) {
      if (act[n]) {
#pragma unroll
        for (int i = 0; i < 8; ++i) {
          hh[n][2 * i] = b2f(gp[(size_t)(cw[n][i] & 0xFFFFu) * 32 + col]);
          hh[n][2 * i + 1] = b2f(gp[(size_t)(cw[n][i] >> 16) * 32 + col]);
        }
      }
    }
#pragma unroll
    for (int n = 0; n < 4; ++n) {
      if (act[n]) {
        float s0 = (hh[n][0] + hh[n][1]) + (hh[n][2] + hh[n][3]);
        float s1 = (hh[n][4] + hh[n][5]) + (hh[n][6] + hh[n][7]);
        float s2 = (hh[n][8] + hh[n][9]) + (hh[n][10] + hh[n][11]);
        float s3 = (hh[n][12] + hh[n][13]) + (hh[n][14] + hh[n][15]);
        acc[n] += (s0 + s1) + (s2 + s3);
      }
    }
  }
  int c = col + pass * 32;
  float bv = b2f(bias[c]);
  float wfv = w2f[c];
#pragma unroll
  for (int n = 0; n < 4; ++n) {
    float val = fmaxf(dvl[n] * acc[n] + bv, 0.0f) * wfv;
    for (int o = 16; o > 0; o >>= 1) val += __shfl_xor(val, o);
    if (col == n && ok[n]) {
      int nv = vb + n;
      float rr = dvl[n] * val;
      tvec[nv] = pass ? (tvec[nv] + rr) : rr;
    }
  }
}

// Scalar agg + sigmoid: four nodes/wave, 16 lanes each.
// z[v] = dv*(sum tscaled[s] + tscaled[v]) + cbias; sentinel pads add 0.
__global__ __launch_bounds__(256) void k_aggz(const float* __restrict__ tvec,
                                              const int* __restrict__ rowstart,
                                              const int* __restrict__ cnt,
                                              const u16* __restrict__ csr,
                                              const float* __restrict__ cbias,
                                              void* __restrict__ out,
                                              const int* __restrict__ flags) {
  int tid = threadIdx.x;
  int wave = tid >> 6, lane = tid & 63;
  int sub = lane >> 4, slot = lane & 15;
  int v = blockIdx.x * 16 + wave * 4 + sub;  // NN%16==0 -> v < NN
  int rs = rowstart[v];
  int cv = cnt[v];
  int pdeg = (cv + 15) & ~15;
  float acc = 0.f;
  for (int j = slot; j < pdeg; j += 16) acc += tvec[csr[rs + j]];
  for (int o = 8; o > 0; o >>= 1) acc += __shfl_xor(acc, o);
  if (slot == 0) {
    float dv = rsqrtf((float)(cv + 1));
    float z = dv * (acc + tvec[v]) + cbias[0];
    float sg = 1.0f / (1.0f + __expf(-z));
    if (flags[0]) ((u16*)out)[v] = f2b(sg);
    else ((float*)out)[v] = sg;
  }
}

extern "C" void kernel_launch(void* const* d_in, const int* in_sizes, int n_in,
                              void* d_out, int out_size, void* d_ws, size_t ws_size,
                              hipStream_t stream) {
  const void* x = d_in[0];
  const int* ei = (const int*)d_in[1];
  const void* W1 = d_in[2];
  const u16* b1 = (const u16*)d_in[3];
  const void* W2 = d_in[4];
  const u16* b2 = (const u16*)d_in[5];
  const void* Wfc = d_in[6];
  const u16* bfc = (const u16*)d_in[7];

  int E = in_sizes[1] / 2;
  const int* src = ei;
  const int* dst = ei + E;

  char* base = (char*)d_ws;
  size_t off = 0;
  auto alloc = [&](size_t bytes) {
    void* p = base + off;
    off = (off + bytes + 255) & ~(size_t)255;
    return p;
  };
  int* flags = (int*)alloc(8 * 4);
  u16* W1h = (u16*)alloc((size_t)FIN * 64 * 2);
  u16* W1l = (u16*)alloc((size_t)FIN * 64 * 2);
  float* w2f = (float*)alloc(64 * 4);
  float* cbias = (float*)alloc(4);
  int* rowstart = (int*)alloc((size_t)NN * 4);
  int* gtail = (int*)alloc((size_t)NREG * 4);   // gtail+cnt contiguous: one memset
  int* cnt = (int*)alloc((size_t)NN * 4);
  u32* bucket = (u32*)alloc((size_t)NREG * RCAP * 4);
  u16* csr = (u16*)alloc((size_t)NREG * SLAB * 2);
  u16* g0 = (u16*)alloc((size_t)(NN + 1) * 32 * 2);  // cols 0..31 + 0 row
  u16* g1 = (u16*)alloc((size_t)(NN + 1) * 32 * 2);  // cols 32..63 + 0 row
  float* tvec = (float*)alloc((size_t)(NN + 1) * 4);  // tscaled + 0 sentinel

  size_t zbytes = (size_t)((char*)(cnt + NN) - (char*)gtail);
  hipMemsetAsync(gtail, 0, zbytes, stream);  // zeroes gtail AND cnt
  // 1) prep (frag tables, w2f, cbias, flags, sentinels) + binA (+degree atomics)
  k_prep_binA<<<289, 256, 0, stream>>>(
      (const u32*)x, in_sizes[0] / 2, W1, in_sizes[2] / 2, W2, in_sizes[4] / 2,
      Wfc, in_sizes[6] / 2, b2, bfc, W1h, W1l, w2f, cbias, flags, src, dst, E,
      bucket, gtail, cnt, g0, g1, tvec);
  // 2) region scan->rowstart + CSR scatter+pad (196 blocks)
  //    + dinv-scaled x@W1 MFMA GEMM into split g0/g1 (782 blocks)
  k_gemm_scatter<<<NREG + (NT + 3) / 4, 256, 0, stream>>>(
      bucket, gtail, rowstart, cnt, csr, x, W1h, W1l, g0, g1, flags);
  // 3) layer-1 agg halves: each pass gathers from one L2-resident 3.2 MB table
  k_agg1p<<<NB_AGG, 256, 0, stream>>>(g0, rowstart, cnt, csr, b1, w2f, tvec, 0);
  k_agg1p<<<NB_AGG, 256, 0, stream>>>(g1, rowstart, cnt, csr, b1, w2f, tvec, 1);
  // 4) scalar agg + sigmoid -> out
  k_aggz<<<NN / 16, 256, 0, stream>>>(tvec, rowstart, cnt, csr, cbias, d_out,
                                      flags);
}